// Round 14
// baseline (131.490 us; speedup 1.0000x reference)
//
#include <hip/hip_runtime.h>
#include <math.h>

#define NCH 32
#define TPB 256     // 4 independent waves/block; no LDS, no barriers

// cos(2*pi*j/32), sin(2*pi*j/32) — constexpr: all indexed with literal
// constants below, so every coefficient folds to an immediate.
constexpr float CT[32] = {
   1.0f,                 0.9807852804032304f,  0.9238795325112867f,  0.8314696123025452f,
   0.7071067811865476f,  0.5555702330196022f,  0.3826834323650898f,  0.1950903220161283f,
   0.0f,                -0.1950903220161283f, -0.3826834323650898f, -0.5555702330196022f,
  -0.7071067811865476f, -0.8314696123025452f, -0.9238795325112867f, -0.9807852804032304f,
  -1.0f,                -0.9807852804032304f, -0.9238795325112867f, -0.8314696123025452f,
  -0.7071067811865476f, -0.5555702330196022f, -0.3826834323650898f, -0.1950903220161283f,
   0.0f,                 0.1950903220161283f,  0.3826834323650898f,  0.5555702330196022f,
   0.7071067811865476f,  0.8314696123025452f,  0.9238795325112867f,  0.9807852804032304f
};
constexpr float ST[32] = {
   0.0f,                 0.1950903220161283f,  0.3826834323650898f,  0.5555702330196022f,
   0.7071067811865476f,  0.8314696123025452f,  0.9238795325112867f,  0.9807852804032304f,
   1.0f,                 0.9807852804032304f,  0.9238795325112867f,  0.8314696123025452f,
   0.7071067811865476f,  0.5555702330196022f,  0.3826834323650898f,  0.1950903220161283f,
   0.0f,                -0.1950903220161283f, -0.3826834323650898f, -0.5555702330196022f,
  -0.7071067811865476f, -0.8314696123025452f, -0.9238795325112867f, -0.9807852804032304f,
  -1.0f,                -0.9807852804032304f, -0.9238795325112867f, -0.8314696123025452f,
  -0.7071067811865476f, -0.5555702330196022f, -0.3826834323650898f, -0.1950903220161283f
};

// Complex nonlinearity (forward scale folded into w1, inverse scale + 0.5 of
// cosh/sinh folded into w2). X = inv*(sr - i*si).
__device__ __forceinline__ void cnonlin(float sr, float si,
    float w1r, float w1i, float w2r, float w2i, float& G, float& H)
{
    const float p = fmaf(sr, w1r, si * w1i);
    const float q = fmaf(sr, w1i, -(si * w1r));
    float sp, cp;
    __sincosf(p, &sp, &cp);
    const float eq = __expf(q), en = __expf(-q);
    const float sA = sp * (eq + en);
    const float sB = cp * (eq - en);
    G = fmaf(sA, w2r, -(sB * w2i));
    H = fmaf(sA, w2i, sB * w2r);
}

__device__ __forceinline__ float cnonlin_real(float sr,
    float w1r, float w1i, float w2r, float w2i)
{
    const float p = sr * w1r;
    const float q = sr * w1i;
    float sp, cp;
    __sincosf(p, &sp, &cp);
    const float eq = __expf(q), en = __expf(-q);
    return fmaf(sp * (eq + en), w2r, -((cp * (eq - en)) * w2i));
}

// Forward bin-pair (k, 16-k). U* = em/ep scalars, V* = op/om scalars.
// All CT/ST indices are integer-constant expressions -> immediates.
#define KPAIR(K, U1,U2,U3,U4,U5,U6,U7, V1,V2,V3,V4,V5,V6,V7, TB, S8)          \
  {                                                                           \
    const float SrE = fmaf(CT[(2*(K))&31], U2, fmaf(CT[(4*(K))&31], U4,       \
                      CT[(6*(K))&31] * U6));                                  \
    const float SrO = fmaf(CT[(K)&31], U1, fmaf(CT[(3*(K))&31], U3,           \
                      fmaf(CT[(5*(K))&31], U5, CT[(7*(K))&31] * U7)));        \
    const float SiE = fmaf(ST[(2*(K))&31], V2, fmaf(ST[(4*(K))&31], V4,       \
                      ST[(6*(K))&31] * V6));                                  \
    const float SiO = fmaf(ST[(K)&31], V1, fmaf(ST[(3*(K))&31], V3,           \
                      fmaf(ST[(5*(K))&31], V5, ST[(7*(K))&31] * V7)));        \
    const float siEO  = SiE + SiO + (S8);                                     \
    const float siOmE = SiO - SiE - (S8);                                     \
    const float srk   = (TB) + SrE + SrO;                                     \
    const float srkp  = (TB) + (SrE - SrO);                                   \
    float Gk, Hk, Gkp, Hkp;                                                   \
    cnonlin(srk,  siEO,  c1r[K]*inv,  c1i[K]*inv,  c2r[K]*inv,  c2i[K]*inv,   \
            Gk, Hk);                                                          \
    cnonlin(srkp, siOmE, c1r[16-(K)]*inv, c1i[16-(K)]*inv,                    \
            c2r[16-(K)]*inv, c2i[16-(K)]*inv, Gkp, Hkp);                      \
    Gp##K = Gk + Gkp;  Gm##K = Gk - Gkp;                                      \
    Hp##K = Hk + Hkp;  Hm##K = Hk - Hkp;                                      \
  }

// Inverse output quad for pair (n, 32-n, 16-n, 16+n). G*/H* = Gm/Gp, Hp/Hm.
#define NPAIR(N, G1,G2,G3,G4,G5,G6,G7, H1,H2,H3,H4,H5,H6,H7, W1, W2,          \
              YA, YB, YC, YD)                                                 \
  {                                                                           \
    const float CE = fmaf(CT[(2*(N))&31], G2, fmaf(CT[(4*(N))&31], G4,        \
                     CT[(6*(N))&31] * G6));                                   \
    const float CO = fmaf(CT[(N)&31], G1, fmaf(CT[(3*(N))&31], G3,            \
                     fmaf(CT[(5*(N))&31], G5, CT[(7*(N))&31] * G7)));         \
    const float SE = fmaf(ST[(2*(N))&31], H2, fmaf(ST[(4*(N))&31], H4,        \
                     ST[(6*(N))&31] * H6));                                   \
    const float SO = fmaf(ST[(N)&31], H1, fmaf(ST[(3*(N))&31], H3,            \
                     fmaf(ST[(5*(N))&31], H5, ST[(7*(N))&31] * H7)));         \
    const float a = CE + CO, b = CE - CO, c = SE + SO, d = SE - SO;           \
    YA = (W1) + a - c;    /* y[n]    */                                       \
    YB = (W2) + a + c;    /* y[32-n] */                                       \
    YC = (W2) + b + d;    /* y[16-n] */                                       \
    YD = (W1) + b - d;    /* y[16+n] */                                       \
  }

__global__ __launch_bounds__(TPB) void fcm_kernel(
    const float* __restrict__ x,
    const float* __restrict__ c1r, const float* __restrict__ c1i,
    const float* __restrict__ c2r, const float* __restrict__ c2i,
    float* __restrict__ out)
{
    // one row (32 contiguous floats = 128 B) per thread; everything in
    // NAMED SCALARS — no arrays, no runtime indexing, no scratch possible.
    const long long row = (long long)blockIdx.x * TPB + threadIdx.x;
    const float* xptr = x + row * NCH;
    float*       optr = out + row * NCH;
    const float inv = 0.17677669529663687f;          // 1/sqrt(32)

    const float4 L0 = *reinterpret_cast<const float4*>(xptr +  0);
    const float4 L1 = *reinterpret_cast<const float4*>(xptr +  4);
    const float4 L2 = *reinterpret_cast<const float4*>(xptr +  8);
    const float4 L3 = *reinterpret_cast<const float4*>(xptr + 12);
    const float4 L4 = *reinterpret_cast<const float4*>(xptr + 16);
    const float4 L5 = *reinterpret_cast<const float4*>(xptr + 20);
    const float4 L6 = *reinterpret_cast<const float4*>(xptr + 24);
    const float4 L7 = *reinterpret_cast<const float4*>(xptr + 28);

    const float xr0 =L0.x, xr1 =L0.y, xr2 =L0.z, xr3 =L0.w;
    const float xr4 =L1.x, xr5 =L1.y, xr6 =L1.z, xr7 =L1.w;
    const float xr8 =L2.x, xr9 =L2.y, xr10=L2.z, xr11=L2.w;
    const float xr12=L3.x, xr13=L3.y, xr14=L3.z, xr15=L3.w;
    const float xr16=L4.x, xr17=L4.y, xr18=L4.z, xr19=L4.w;
    const float xr20=L5.x, xr21=L5.y, xr22=L5.z, xr23=L5.w;
    const float xr24=L6.x, xr25=L6.y, xr26=L6.z, xr27=L6.w;
    const float xr28=L7.x, xr29=L7.y, xr30=L7.z, xr31=L7.w;

    // ev/od (m paired with 32-m)
    const float ev1 =xr1 +xr31, od1 =xr1 -xr31;
    const float ev2 =xr2 +xr30, od2 =xr2 -xr30;
    const float ev3 =xr3 +xr29, od3 =xr3 -xr29;
    const float ev4 =xr4 +xr28, od4 =xr4 -xr28;
    const float ev5 =xr5 +xr27, od5 =xr5 -xr27;
    const float ev6 =xr6 +xr26, od6 =xr6 -xr26;
    const float ev7 =xr7 +xr25, od7 =xr7 -xr25;
    const float e8  =xr8 +xr24, o8  =xr8 -xr24;
    const float ev9 =xr9 +xr23, od9 =xr9 -xr23;
    const float ev10=xr10+xr22, od10=xr10-xr22;
    const float ev11=xr11+xr21, od11=xr11-xr21;
    const float ev12=xr12+xr20, od12=xr12-xr20;
    const float ev13=xr13+xr19, od13=xr13-xr19;
    const float ev14=xr14+xr18, od14=xr14-xr18;
    const float ev15=xr15+xr17, od15=xr15-xr17;
    const float xp_ = xr0 + xr16, xm_ = xr0 - xr16;

    // second-level combos (m paired with 16-m)
    const float ep1=ev1+ev15, em1=ev1-ev15, op1=od1+od15, om1=od1-od15;
    const float ep2=ev2+ev14, em2=ev2-ev14, op2=od2+od14, om2=od2-od14;
    const float ep3=ev3+ev13, em3=ev3-ev13, op3=od3+od13, om3=od3-od13;
    const float ep4=ev4+ev12, em4=ev4-ev12, op4=od4+od12, om4=od4-od12;
    const float ep5=ev5+ev11, em5=ev5-ev11, op5=od5+od11, om5=od5-od11;
    const float ep6=ev6+ev10, em6=ev6-ev10, op6=od6+od10, om6=od6-od10;
    const float ep7=ev7+ev9,  em7=ev7-ev9,  op7=od7+od9,  om7=od7-od9;

    // specials k = 0, 16, 8
    float G0, G16, G8, H8;
    {
        const float A  = ep2 + ep4 + ep6;
        const float B  = ep1 + ep3 + ep5 + ep7;
        const float b0 = xp_ + e8;
        G0  = cnonlin_real(b0 + A + B,  c1r[0]*inv,  c1i[0]*inv,
                           c2r[0]*(0.5f*inv),  c2i[0]*(0.5f*inv));
        G16 = cnonlin_real(b0 + A - B,  c1r[16]*inv, c1i[16]*inv,
                           c2r[16]*(0.5f*inv), c2i[16]*(0.5f*inv));
        const float sr8 = b0 - ep2 + ep4 - ep6;
        const float si8 = om1 - om3 + om5 - om7;
        cnonlin(sr8, si8, c1r[8]*inv, c1i[8]*inv, c2r[8]*inv, c2i[8]*inv,
                G8, H8);
    }

    float Gp1,Gm1,Hp1,Hm1, Gp2,Gm2,Hp2,Hm2, Gp3,Gm3,Hp3,Hm3, Gp4,Gm4,Hp4,Hm4,
          Gp5,Gm5,Hp5,Hm5, Gp6,Gm6,Hp6,Hm6, Gp7,Gm7,Hp7,Hm7;

    // odd k: U=em, V=op, TB=xm_, S8=+/-o8; even k: U=ep, V=om, TB=xp_+/-e8
    KPAIR(1, em1,em2,em3,em4,em5,em6,em7, op1,op2,op3,op4,op5,op6,op7, xm_,      o8)
    KPAIR(2, ep1,ep2,ep3,ep4,ep5,ep6,ep7, om1,om2,om3,om4,om5,om6,om7, xp_-e8, 0.0f)
    KPAIR(3, em1,em2,em3,em4,em5,em6,em7, op1,op2,op3,op4,op5,op6,op7, xm_,     -o8)
    KPAIR(4, ep1,ep2,ep3,ep4,ep5,ep6,ep7, om1,om2,om3,om4,om5,om6,om7, xp_+e8, 0.0f)
    KPAIR(5, em1,em2,em3,em4,em5,em6,em7, op1,op2,op3,op4,op5,op6,op7, xm_,      o8)
    KPAIR(6, ep1,ep2,ep3,ep4,ep5,ep6,ep7, om1,om2,om3,om4,om5,om6,om7, xp_-e8, 0.0f)
    KPAIR(7, em1,em2,em3,em4,em5,em6,em7, op1,op2,op3,op4,op5,op6,op7, xm_,     -o8)

    // inverse
    const float Dp = G0 + G16, Dm = G0 - G16;
    float y0,y1,y2,y3,y4,y5,y6,y7,y8,y9,y10,y11,y12,y13,y14,y15,
          y16,y17,y18,y19,y20,y21,y22,y23,y24,y25,y26,y27,y28,y29,y30,y31;

    {   // specials n = 0, 16, 8, 24
        const float GA = Gp2 + Gp4 + Gp6;
        const float GB = Gp1 + Gp3 + Gp5 + Gp7;
        const float b8 = Dp + G8;
        y0  = b8 + GA + GB;
        y16 = b8 + GA - GB;
        const float C8 = -Gp2 + Gp4 - Gp6;
        const float S8v =  Hm1 - Hm3 + Hm5 - Hm7;
        const float t8 = b8 + C8;
        y8  = t8 - S8v;
        y24 = t8 + S8v;
    }

    // odd n: G=Gm, H=Hp, w from Dm -/+ H8; even n: G=Gp, H=Hm, w = Dp +/- G8
    NPAIR(1, Gm1,Gm2,Gm3,Gm4,Gm5,Gm6,Gm7, Hp1,Hp2,Hp3,Hp4,Hp5,Hp6,Hp7,
             Dm - H8, Dm + H8, y1, y31, y15, y17)
    NPAIR(2, Gp1,Gp2,Gp3,Gp4,Gp5,Gp6,Gp7, Hm1,Hm2,Hm3,Hm4,Hm5,Hm6,Hm7,
             Dp - G8, Dp - G8, y2, y30, y14, y18)
    NPAIR(3, Gm1,Gm2,Gm3,Gm4,Gm5,Gm6,Gm7, Hp1,Hp2,Hp3,Hp4,Hp5,Hp6,Hp7,
             Dm + H8, Dm - H8, y3, y29, y13, y19)
    NPAIR(4, Gp1,Gp2,Gp3,Gp4,Gp5,Gp6,Gp7, Hm1,Hm2,Hm3,Hm4,Hm5,Hm6,Hm7,
             Dp + G8, Dp + G8, y4, y28, y12, y20)
    NPAIR(5, Gm1,Gm2,Gm3,Gm4,Gm5,Gm6,Gm7, Hp1,Hp2,Hp3,Hp4,Hp5,Hp6,Hp7,
             Dm - H8, Dm + H8, y5, y27, y11, y21)
    NPAIR(6, Gp1,Gp2,Gp3,Gp4,Gp5,Gp6,Gp7, Hm1,Hm2,Hm3,Hm4,Hm5,Hm6,Hm7,
             Dp - G8, Dp - G8, y6, y26, y10, y22)
    NPAIR(7, Gm1,Gm2,Gm3,Gm4,Gm5,Gm6,Gm7, Hp1,Hp2,Hp3,Hp4,Hp5,Hp6,Hp7,
             Dm + H8, Dm - H8, y7, y25, y9, y23)

    *reinterpret_cast<float4*>(optr +  0) = make_float4(y0,  y1,  y2,  y3);
    *reinterpret_cast<float4*>(optr +  4) = make_float4(y4,  y5,  y6,  y7);
    *reinterpret_cast<float4*>(optr +  8) = make_float4(y8,  y9,  y10, y11);
    *reinterpret_cast<float4*>(optr + 12) = make_float4(y12, y13, y14, y15);
    *reinterpret_cast<float4*>(optr + 16) = make_float4(y16, y17, y18, y19);
    *reinterpret_cast<float4*>(optr + 20) = make_float4(y20, y21, y22, y23);
    *reinterpret_cast<float4*>(optr + 24) = make_float4(y24, y25, y26, y27);
    *reinterpret_cast<float4*>(optr + 28) = make_float4(y28, y29, y30, y31);
}

extern "C" void kernel_launch(void* const* d_in, const int* in_sizes, int n_in,
                              void* d_out, int out_size, void* d_ws, size_t ws_size,
                              hipStream_t stream) {
    const float* x   = (const float*)d_in[0];
    const float* c1r = (const float*)d_in[1];
    const float* c1i = (const float*)d_in[2];
    const float* c2r = (const float*)d_in[3];
    const float* c2i = (const float*)d_in[4];
    float* out = (float*)d_out;

    const int total  = in_sizes[0];          // 64*8192*32 floats
    const int blocks = total / (TPB * NCH);  // 2048 blocks x 256 threads
    fcm_kernel<<<blocks, TPB, 0, stream>>>(x, c1r, c1i, c2r, c2i, out);
}